// Round 1
// 1070.972 us; speedup vs baseline: 1.0043x; 1.0043x over previous
//
#include <hip/hip_runtime.h>
#include <stdint.h>
#include <stddef.h>

// Problem constants (fixed by setup_inputs).
#define B_ROWS 1024
#define D_DIM  1024
#define N_MEM  100000
#define C_CLS  1000
#define K_TOP  5

// 256x256 tile, BK=64, 8 waves (2M x 4N), 16x16x32 MFMA, 2-K-tile double buffer.
#define BM 256
#define BN 256
#define BKT 64
#define NKT (D_DIM / BKT)                  // 16
#define NT_TILES ((N_MEM + BN - 1) / BN)   // 391
#define NPAD (NT_TILES * BN)               // 100096 = 391*256 exactly
#define BT_TILES (B_ROWS / BM)             // 4
#define NT_PER_XCD 49                      // XCDs 0..6 own 49 nt-tiles, XCD 7 owns 48
#define GRID_GEMM (8 * NT_PER_XCD * BT_TILES)  // 1568 (16 dummy blocks early-out)

typedef __bf16 bf16;
typedef bf16 bf16x4 __attribute__((ext_vector_type(4)));
typedef bf16 bf16x8 __attribute__((ext_vector_type(8)));
typedef float f32x4 __attribute__((ext_vector_type(4)));

#define MFMA16(a, b, c) __builtin_amdgcn_mfma_f32_16x16x32_bf16((a), (b), (c), 0, 0, 0)
// raw barrier (no vmcnt drain!) + compiler fences so plain LDS loads can't cross it
#define BARRIER() do { asm volatile("" ::: "memory"); \
                       __builtin_amdgcn_s_barrier();  \
                       asm volatile("" ::: "memory"); } while (0)
#define WAITVM(N) asm volatile("s_waitcnt vmcnt(" #N ")" ::: "memory")

// sorted-descending top-5 insert, all constant indices (no scratch spill)
__device__ __forceinline__ void insert5(float v, int n, float tv[K_TOP], int ti[K_TOP]) {
#pragma unroll
  for (int j = 0; j < K_TOP; ++j) {
    bool gt = v > tv[j];
    float ov = tv[j]; int oi = ti[j];
    tv[j] = gt ? v : ov;  ti[j] = gt ? n : oi;
    v = gt ? ov : v;      n = gt ? oi : n;
  }
}

// -------------------- K1: normalize rows of features -> bf16 --------------------
__global__ __launch_bounds__(256) void k_normalize(const float* __restrict__ F,
                                                   bf16* __restrict__ X) {
  int row = blockIdx.x;
  int tid = threadIdx.x;
  const float4* fr = (const float4*)(F + (size_t)row * D_DIM);
  float4 v = fr[tid];                     // 256 threads * 4 = 1024 = D
  float s = v.x * v.x + v.y * v.y + v.z * v.z + v.w * v.w;
  for (int off = 32; off > 0; off >>= 1) s += __shfl_down(s, off, 64);
  __shared__ float wred[4];
  if ((tid & 63) == 0) wred[tid >> 6] = s;
  __syncthreads();
  float tot = wred[0] + wred[1] + wred[2] + wred[3];
  float inv = 1.0f / fmaxf(sqrtf(tot), 1e-12f);
  bf16x4 o;
  o[0] = (bf16)(v.x * inv);
  o[1] = (bf16)(v.y * inv);
  o[2] = (bf16)(v.z * inv);
  o[3] = (bf16)(v.w * inv);
  *(bf16x4*)(X + (size_t)row * D_DIM + (size_t)tid * 4) = o;
}

// -------------------- K2: feat_memory fp32 -> bf16 (zero-fill pad rows) --------
__global__ __launch_bounds__(256) void k_convert(const float* __restrict__ FM,
                                                 bf16* __restrict__ FMB,
                                                 int total8, int pad8) {
  int i = blockIdx.x * 256 + threadIdx.x;   // index of 8-float group
  if (i >= pad8) return;
  bf16x8 o;
  if (i < total8) {
    float4 a = ((const float4*)FM)[2 * i];
    float4 b = ((const float4*)FM)[2 * i + 1];
    o[0] = (bf16)a.x; o[1] = (bf16)a.y; o[2] = (bf16)a.z; o[3] = (bf16)a.w;
    o[4] = (bf16)b.x; o[5] = (bf16)b.y; o[6] = (bf16)b.z; o[7] = (bf16)b.w;
  } else {
#pragma unroll
    for (int e = 0; e < 8; ++e) o[e] = (bf16)0.f;   // pad rows 100000..100095
  }
  ((bf16x8*)FMB)[i] = o;                   // 16B store
}

// -------------------- K3: 256^2 deep-pipelined bf16 MFMA GEMM + top-5 ----------
__device__ __forceinline__ void gl_lds16(const bf16* g, char* l) {
  __builtin_amdgcn_global_load_lds((__attribute__((address_space(1))) void*)g,
                                   (__attribute__((address_space(3))) void*)l,
                                   16, 0, 0);
}

// stage one 128x64 half-tile (16 KB): 2 x global_load_lds(16B) per thread.
// global source is pre-swizzled (chunk j_src = j_slot ^ (row&7)); LDS dest linear.
#define STAGE_HALF(g, off, rbase, k0) do {                                     \
    gl_lds16((g) + (size_t)(rbase) * D_DIM + (k0),      lds + (off) + d0);     \
    gl_lds16((g) + (size_t)((rbase) + 64) * D_DIM + (k0), lds + (off) + d1);   \
  } while (0)

__global__ __launch_bounds__(512, 2) void k_gemm_topk(const bf16* __restrict__ X,
                                                      const bf16* __restrict__ FMB,
                                                      const int* __restrict__ IDX,
                                                      float2* __restrict__ CAND) {
  extern __shared__ char lds[];            // 128 KB: 2 buffers x (A 2x16K + B 2x16K)
  int bid = blockIdx.x;
  int xcd = bid & 7;                       // round-robin dispatch heuristic
  int jj = bid >> 3;
  int cnt = (xcd < 7) ? NT_PER_XCD : (NT_TILES - 7 * NT_PER_XCD);  // 49 / 48
  if (jj >= 4 * cnt) return;               // uniform whole-block early-out
  int nt = xcd * NT_PER_XCD + (jj >> 2);   // each XCD owns contiguous nt range
  int bt = jj & 3;                         // bt fastest: 4 siblings share B panel in L2
  size_t row0 = (size_t)bt * BM;
  size_t col0 = (size_t)nt * BN;

  int tid = threadIdx.x;
  int lane = tid & 63;
  int wv = tid >> 6;
  int wm = wv >> 2, wn = wv & 3;           // 2x4 wave grid; wave output = 128x64
  int frow = lane & 15, q = lane >> 4;
  // XOR-swizzled chunk byte offsets for ds_read_b128 (row&7 == frow&7 here)
  int cs0 = ((q ^ (frow & 7)) * 16);       // kk=0: k 0..31
  int cs1 = (((q + 4) ^ (frow & 7)) * 16); // kk=1: k 32..63

  // staging source (per-thread, l-invariant): chunk pre-swizzle
  int arow0 = tid >> 3;
  int jsrc = (tid & 7) ^ (arow0 & 7);
  const bf16* gA = X   + ((size_t)row0 + arow0) * D_DIM + jsrc * 8;
  const bf16* gB = FMB + ((size_t)col0 + arow0) * D_DIM + jsrc * 8;
  int d0 = tid * 16;                       // LDS dest byte (l=0)
  int d1 = 8192 + tid * 16;                // LDS dest byte (l=1)

  // ---- prologue: stage tile0 (loads 1-8) and tile1 (loads 9-16) ----
  STAGE_HALF(gA, 0,     0,   0);
  STAGE_HALF(gA, 16384, 128, 0);
  STAGE_HALF(gB, 32768, 0,   0);
  STAGE_HALF(gB, 49152, 128, 0);
  STAGE_HALF(gA, 65536 + 0,     0,   BKT);
  STAGE_HALF(gA, 65536 + 16384, 128, BKT);
  STAGE_HALF(gB, 65536 + 32768, 0,   BKT);
  STAGE_HALF(gB, 65536 + 49152, 128, BKT);

  f32x4 acc[8][4];
#pragma unroll
  for (int mi = 0; mi < 8; ++mi)
#pragma unroll
    for (int ni = 0; ni < 4; ++ni)
      acc[mi][ni] = (f32x4){0.f, 0.f, 0.f, 0.f};

  WAITVM(8);                               // tile0 landed; tile1 still in flight
  BARRIER();

  // ---- main loop: tile kt from buf[kt&1]; stage tile kt+2 into same buffer ----
  // 4 phases/tile: P1 {af(mh0)+bf(nh0) reads, 16 MFMA}  P2 {bf(nh1), 16 MFMA}
  //               P3 {af(mh1) + stage B(kt+2), 16 MFMA} P4 {stage A(kt+2), 16 MFMA}
  // counted vmcnt(8) ONLY at tile boundary (tile kt+2's 8 loads stay in flight).
#pragma unroll 2
  for (int kt = 0; kt < NKT; ++kt) {
    char* buf = lds + ((kt & 1) << 16);
    const char* Ab = buf + wm * 16384 + frow * 128;
    const char* Bb = buf + 32768 + ((wn >> 1) * 16384) + ((wn & 1) * 8192) + frow * 128;
    int bufoff = (kt & 1) << 16;
    int k2 = (kt + 2) * BKT;
    bool do_stage = (kt < NKT - 2);
    bf16x8 af[4][2], bfr[4][2];

    // ---------- phase 1: af mh=0 (8 reads) + bf nh=0 (4 reads) ----------
#pragma unroll
    for (int mi = 0; mi < 4; ++mi) {
      af[mi][0] = *(const bf16x8*)(Ab + mi * 2048 + cs0);
      af[mi][1] = *(const bf16x8*)(Ab + mi * 2048 + cs1);
    }
#pragma unroll
    for (int nb = 0; nb < 2; ++nb) {
      bfr[nb][0] = *(const bf16x8*)(Bb + nb * 2048 + cs0);
      bfr[nb][1] = *(const bf16x8*)(Bb + nb * 2048 + cs1);
    }
    BARRIER();
    __builtin_amdgcn_s_setprio(1);
#pragma unroll
    for (int mi = 0; mi < 4; ++mi)
#pragma unroll
      for (int nb = 0; nb < 2; ++nb) {
        acc[mi][nb] = MFMA16(af[mi][0], bfr[nb][0], acc[mi][nb]);
        acc[mi][nb] = MFMA16(af[mi][1], bfr[nb][1], acc[mi][nb]);
      }
    __builtin_amdgcn_s_setprio(0);
    BARRIER();

    // ---------- phase 2: bf nh=1 (4 reads) ----------
#pragma unroll
    for (int nb = 2; nb < 4; ++nb) {
      bfr[nb][0] = *(const bf16x8*)(Bb + nb * 2048 + cs0);
      bfr[nb][1] = *(const bf16x8*)(Bb + nb * 2048 + cs1);
    }
    BARRIER();
    __builtin_amdgcn_s_setprio(1);
#pragma unroll
    for (int mi = 0; mi < 4; ++mi)
#pragma unroll
      for (int nb = 2; nb < 4; ++nb) {
        acc[mi][nb] = MFMA16(af[mi][0], bfr[nb][0], acc[mi][nb]);
        acc[mi][nb] = MFMA16(af[mi][1], bfr[nb][1], acc[mi][nb]);
      }
    __builtin_amdgcn_s_setprio(0);
    BARRIER();

    // ---------- phase 3: af mh=1 (8 reads); stage B halves of kt+2 ----------
    // (all waves' B reads of this buffer retired before P2's closing barrier)
#pragma unroll
    for (int mi = 0; mi < 4; ++mi) {
      af[mi][0] = *(const bf16x8*)(Ab + 8192 + mi * 2048 + cs0);
      af[mi][1] = *(const bf16x8*)(Ab + 8192 + mi * 2048 + cs1);
    }
    if (do_stage) {
      STAGE_HALF(gB, bufoff + 32768, 0,   k2);
      STAGE_HALF(gB, bufoff + 49152, 128, k2);
    }
    BARRIER();
    __builtin_amdgcn_s_setprio(1);
#pragma unroll
    for (int mi = 0; mi < 4; ++mi)
#pragma unroll
      for (int nb = 2; nb < 4; ++nb) {
        acc[4 + mi][nb] = MFMA16(af[mi][0], bfr[nb][0], acc[4 + mi][nb]);
        acc[4 + mi][nb] = MFMA16(af[mi][1], bfr[nb][1], acc[4 + mi][nb]);
      }
    __builtin_amdgcn_s_setprio(0);
    BARRIER();

    // ---------- phase 4: stage A halves of kt+2; reuse af(mh1)+bf(nh0) ----------
    if (do_stage) {
      STAGE_HALF(gA, bufoff + 0,     0,   k2);
      STAGE_HALF(gA, bufoff + 16384, 128, k2);
    }
    BARRIER();
    __builtin_amdgcn_s_setprio(1);
#pragma unroll
    for (int mi = 0; mi < 4; ++mi)
#pragma unroll
      for (int nb = 0; nb < 2; ++nb) {
        acc[4 + mi][nb] = MFMA16(af[mi][0], bfr[nb][0], acc[4 + mi][nb]);
        acc[4 + mi][nb] = MFMA16(af[mi][1], bfr[nb][1], acc[4 + mi][nb]);
      }
    __builtin_amdgcn_s_setprio(0);
    // tile boundary: wait so only tile kt+2's 8 loads remain in flight
    if (kt < NKT - 2) { WAITVM(8); } else { WAITVM(0); }
    BARRIER();
  }

  // ---- epilogue 1: scores -> LDS (reuse all 128 KB as 256x256 bf16 tile) ----
  // C/D layout: frag_row=(lane>>4)*4+r, frag_col=lane&15.
  // score layout swizzled: 16B chunk index ^= (row&31) to break the 512B row stride.
  int Rbase = wm * 128 + q * 4;
#pragma unroll
  for (int mi = 0; mi < 8; ++mi)
#pragma unroll
    for (int ni = 0; ni < 4; ++ni) {
      int Cc = wn * 64 + ni * 16 + frow;
      int chunkC = Cc >> 3;
      int e2 = (Cc & 7) * 2;
#pragma unroll
      for (int r = 0; r < 4; ++r) {
        int R = Rbase + mi * 16 + r;
        *(bf16*)(lds + R * 512 + ((chunkC ^ (R & 31)) * 16) + e2) = (bf16)acc[mi][ni][r];
      }
    }
  __syncthreads();

  // ---- epilogue 2: per-row top-5 within this 256-col tile (2 threads/row) ----
  int tr = tid >> 1, h = tid & 1;
  int grow = (int)row0 + tr;
  int self = IDX[grow];
  float tv[K_TOP]; int ti[K_TOP];
#pragma unroll
  for (int j = 0; j < K_TOP; ++j) { tv[j] = -1e30f; ti[j] = -1; }
  int swz = tr & 31;
#pragma unroll
  for (int c8 = 0; c8 < 16; ++c8) {
    int chunk = h * 16 + c8;
    bf16x8 v8 = *(const bf16x8*)(lds + tr * 512 + ((chunk ^ swz) * 16));
#pragma unroll
    for (int e = 0; e < 8; ++e) {
      int gc = (int)col0 + chunk * 8 + e;
      if (gc >= N_MEM || gc == self) continue;    // self-mask == set-to-min trick
      float v = (float)v8[e];
      if (v > tv[K_TOP - 1]) insert5(v, gc, tv, ti);
    }
  }
  // merge the two halves via lane-pair shuffle (snapshot partner first!)
  float pv[K_TOP]; int pi[K_TOP];
#pragma unroll
  for (int j = 0; j < K_TOP; ++j) {
    pv[j] = __shfl_xor(tv[j], 1, 64);
    pi[j] = __shfl_xor(ti[j], 1, 64);
  }
#pragma unroll
  for (int j = 0; j < K_TOP; ++j)
    if (pv[j] > tv[K_TOP - 1]) insert5(pv[j], pi[j], tv, ti);

  if (h == 0) {
    float2* out = CAND + ((size_t)grow * NT_TILES + nt) * K_TOP;
#pragma unroll
    for (int j = 0; j < K_TOP; ++j)
      out[j] = make_float2(tv[j], __int_as_float(ti[j]));
  }
}

// -------------------- shared epilogue: gather pred rows, mean, argmax --------------------
__device__ void gather_mean_argmax(const int* find, const float* __restrict__ P,
                                   float* __restrict__ OUT, int b, int tid) {
  float bestV = -1e30f;
  int bestC = 0;
  for (int c = tid; c < C_CLS; c += 256) {
    float s = 0.f;
    for (int j = 0; j < K_TOP; ++j) s += P[(size_t)find[j] * C_CLS + c];
    float mean = s * (1.0f / K_TOP);
    OUT[(size_t)B_ROWS + (size_t)b * C_CLS + c] = mean;
    if (mean > bestV) { bestV = mean; bestC = c; }   // strict > keeps first occurrence
  }
  __shared__ float rv[256];
  __shared__ int rc[256];
  rv[tid] = bestV; rc[tid] = bestC;
  for (int s = 128; s >= 1; s >>= 1) {
    __syncthreads();
    if (tid < s) {
      float v2 = rv[tid + s]; int c2 = rc[tid + s];
      if (v2 > rv[tid] || (v2 == rv[tid] && c2 < rc[tid])) { rv[tid] = v2; rc[tid] = c2; }
    }
  }
  __syncthreads();
  if (tid == 0) OUT[b] = (float)rc[0];   // jnp.argmax: first max index
}

// -------------------- K4: merge per-tile candidates -> global top-5 + epilogue ------
__global__ __launch_bounds__(256) void k_merge(const float2* __restrict__ CAND,
                                               const float* __restrict__ P,
                                               float* __restrict__ OUT) {
  int b = blockIdx.x;
  int tid = threadIdx.x;
  const float2* row = CAND + (size_t)b * (NT_TILES * K_TOP);

  float tv[K_TOP]; int ti[K_TOP];
  for (int j = 0; j < K_TOP; ++j) { tv[j] = -1e30f; ti[j] = -1; }
  for (int i = tid; i < NT_TILES * K_TOP; i += 256) {
    float2 e = row[i];
    float v = e.x;
    if (v > tv[K_TOP - 1]) insert5(v, __float_as_int(e.y), tv, ti);
  }

  __shared__ float sv[256 * K_TOP];
  __shared__ int si[256 * K_TOP];
  for (int j = 0; j < K_TOP; ++j) { sv[tid * K_TOP + j] = tv[j]; si[tid * K_TOP + j] = ti[j]; }
  for (int s = 128; s >= 1; s >>= 1) {
    __syncthreads();
    if (tid < s) {
      for (int j = 0; j < K_TOP; ++j) {
        float v = sv[(tid + s) * K_TOP + j];
        int n = si[(tid + s) * K_TOP + j];
        if (v > tv[K_TOP - 1]) insert5(v, n, tv, ti);
      }
      for (int j = 0; j < K_TOP; ++j) { sv[tid * K_TOP + j] = tv[j]; si[tid * K_TOP + j] = ti[j]; }
    }
  }
  __syncthreads();
  __shared__ int find[K_TOP];
  if (tid == 0)
    for (int j = 0; j < K_TOP; ++j) {
      int v = si[j];
      find[j] = (v < 0) ? 0 : (v >= N_MEM ? N_MEM - 1 : v);   // defensive clamp
    }
  __syncthreads();
  gather_mean_argmax(find, P, OUT, b, tid);
}

// -------------------- fallback (only if ws_size too small): slow but ws-free --------
__global__ __launch_bounds__(256) void k_naive(const float* __restrict__ F,
                                               const int* __restrict__ IDX,
                                               const float* __restrict__ FM,
                                               const float* __restrict__ P,
                                               float* __restrict__ OUT) {
  int b = blockIdx.x;
  int tid = threadIdx.x;
  __shared__ float wred[4];
  const float4* fr = (const float4*)(F + (size_t)b * D_DIM);
  float4 v = fr[tid];
  float s = v.x * v.x + v.y * v.y + v.z * v.z + v.w * v.w;
  for (int off = 32; off > 0; off >>= 1) s += __shfl_down(s, off, 64);
  if ((tid & 63) == 0) wred[tid >> 6] = s;
  __syncthreads();
  float inv = 1.0f / fmaxf(sqrtf(wred[0] + wred[1] + wred[2] + wred[3]), 1e-12f);
  float4 xv = make_float4(v.x * inv, v.y * inv, v.z * inv, v.w * inv);
  __syncthreads();
  int self = IDX[b];
  __shared__ float ptv[K_TOP];
  __shared__ int pti[K_TOP];
  if (tid < K_TOP) { ptv[tid] = -1e30f; pti[tid] = 0; }
  __syncthreads();
  for (int n = 0; n < N_MEM; ++n) {
    const float4* frow = (const float4*)(FM + (size_t)n * D_DIM);
    float4 fv = frow[tid];
    float p = xv.x * fv.x + xv.y * fv.y + xv.z * fv.z + xv.w * fv.w;
    for (int off = 32; off > 0; off >>= 1) p += __shfl_down(p, off, 64);
    if ((tid & 63) == 0) wred[tid >> 6] = p;
    __syncthreads();
    if (tid == 0 && n != self) {
      float tot = wred[0] + wred[1] + wred[2] + wred[3];
      if (tot > ptv[K_TOP - 1]) {
        int q = K_TOP - 1;
        while (q > 0 && tot > ptv[q - 1]) { ptv[q] = ptv[q - 1]; pti[q] = pti[q - 1]; --q; }
        ptv[q] = tot; pti[q] = n;
      }
    }
    __syncthreads();
  }
  __shared__ int find[K_TOP];
  if (tid < K_TOP) {
    int x = pti[tid];
    find[tid] = (x < 0) ? 0 : (x >= N_MEM ? N_MEM - 1 : x);
  }
  __syncthreads();
  gather_mean_argmax(find, P, OUT, b, tid);
}

// -------------------- launch --------------------
extern "C" void kernel_launch(void* const* d_in, const int* in_sizes, int n_in,
                              void* d_out, int out_size, void* d_ws, size_t ws_size,
                              hipStream_t stream) {
  const float* F  = (const float*)d_in[0];
  const int* IDX  = (const int*)d_in[1];
  const float* FM = (const float*)d_in[2];
  const float* P  = (const float*)d_in[3];
  float* OUT = (float*)d_out;

  const size_t xBytes    = (size_t)B_ROWS * D_DIM * 2;                 // 2 MB
  const size_t fmBytes   = (size_t)NPAD * D_DIM * 2;                   // ~205 MB
  const size_t candBytes = (size_t)B_ROWS * NT_TILES * K_TOP * 8;      // ~16 MB
  const size_t need = xBytes + fmBytes + candBytes;                    // ~223 MB

  if (ws_size >= need) {
    bf16* Xb     = (bf16*)d_ws;
    bf16* FMB    = (bf16*)((char*)d_ws + xBytes);
    float2* CAND = (float2*)((char*)d_ws + xBytes + fmBytes);
    // opt in to 128 KB dynamic LDS (host-side, graph-capture safe)
    (void)hipFuncSetAttribute((const void*)k_gemm_topk,
                              hipFuncAttributeMaxDynamicSharedMemorySize, 131072);
    k_normalize<<<B_ROWS, 256, 0, stream>>>(F, Xb);
    int total8 = N_MEM * D_DIM / 8;                                    // 12,800,000
    int pad8   = NPAD * D_DIM / 8;                                     // 12,812,288
    k_convert<<<(pad8 + 255) / 256, 256, 0, stream>>>(FM, FMB, total8, pad8);
    k_gemm_topk<<<GRID_GEMM, 512, 131072, stream>>>(Xb, FMB, IDX, CAND);
    k_merge<<<B_ROWS, 256, 0, stream>>>(CAND, P, OUT);
  } else {
    // diagnostic fallback: correct but slow, needs zero workspace
    k_naive<<<B_ROWS, 256, 0, stream>>>(F, IDX, FM, P, OUT);
  }
}

// Round 2
// 1039.240 us; speedup vs baseline: 1.0350x; 1.0305x over previous
//
#include <hip/hip_runtime.h>
#include <stdint.h>
#include <stddef.h>

// Problem constants (fixed by setup_inputs).
#define B_ROWS 1024
#define D_DIM  1024
#define N_MEM  100000
#define C_CLS  1000
#define K_TOP  5

// 256x256 tile, BK=64, 8 waves (2M x 4N), 16x16x32 MFMA, 2-K-tile double buffer.
#define BM 256
#define BN 256
#define BKT 64
#define NKT (D_DIM / BKT)                  // 16
#define NT_TILES ((N_MEM + BN - 1) / BN)   // 391
#define NPAD (NT_TILES * BN)               // 100096 = 391*256 exactly
#define BT_TILES (B_ROWS / BM)             // 4
#define NT_PER_XCD 49                      // XCDs 0..6 own 49 nt-tiles, XCD 7 owns 48
#define GRID_GEMM (8 * NT_PER_XCD * BT_TILES)  // 1568 (16 dummy blocks early-out)

typedef __bf16 bf16;
typedef bf16 bf16x4 __attribute__((ext_vector_type(4)));
typedef bf16 bf16x8 __attribute__((ext_vector_type(8)));
typedef float f32x4 __attribute__((ext_vector_type(4)));

#define MFMA16(a, b, c) __builtin_amdgcn_mfma_f32_16x16x32_bf16((a), (b), (c), 0, 0, 0)
// raw barrier (no vmcnt drain!) + compiler fences so LDS/global ops can't cross it
#define BARRIER() do { asm volatile("" ::: "memory"); \
                       __builtin_amdgcn_s_barrier();  \
                       asm volatile("" ::: "memory"); } while (0)
#define WAITVM(N) asm volatile("s_waitcnt vmcnt(" #N ")" ::: "memory")
#define LGKM0()   asm volatile("s_waitcnt lgkmcnt(0)" ::: "memory")
#define VM0()     asm volatile("s_waitcnt vmcnt(0)" ::: "memory")

// sorted-descending top-5 insert, all constant indices (no scratch spill)
__device__ __forceinline__ void insert5(float v, int n, float tv[K_TOP], int ti[K_TOP]) {
#pragma unroll
  for (int j = 0; j < K_TOP; ++j) {
    bool gt = v > tv[j];
    float ov = tv[j]; int oi = ti[j];
    tv[j] = gt ? v : ov;  ti[j] = gt ? n : oi;
    v = gt ? ov : v;      n = gt ? oi : n;
  }
}

// -------------------- K1: normalize rows of features -> bf16 --------------------
__global__ __launch_bounds__(256) void k_normalize(const float* __restrict__ F,
                                                   bf16* __restrict__ X) {
  int row = blockIdx.x;
  int tid = threadIdx.x;
  const float4* fr = (const float4*)(F + (size_t)row * D_DIM);
  float4 v = fr[tid];                     // 256 threads * 4 = 1024 = D
  float s = v.x * v.x + v.y * v.y + v.z * v.z + v.w * v.w;
  for (int off = 32; off > 0; off >>= 1) s += __shfl_down(s, off, 64);
  __shared__ float wred[4];
  if ((tid & 63) == 0) wred[tid >> 6] = s;
  __syncthreads();
  float tot = wred[0] + wred[1] + wred[2] + wred[3];
  float inv = 1.0f / fmaxf(sqrtf(tot), 1e-12f);
  bf16x4 o;
  o[0] = (bf16)(v.x * inv);
  o[1] = (bf16)(v.y * inv);
  o[2] = (bf16)(v.z * inv);
  o[3] = (bf16)(v.w * inv);
  *(bf16x4*)(X + (size_t)row * D_DIM + (size_t)tid * 4) = o;
}

// -------------------- K2: feat_memory fp32 -> bf16 (zero-fill pad rows) --------
__global__ __launch_bounds__(256) void k_convert(const float* __restrict__ FM,
                                                 bf16* __restrict__ FMB,
                                                 int total8, int pad8) {
  int i = blockIdx.x * 256 + threadIdx.x;   // index of 8-float group
  if (i >= pad8) return;
  bf16x8 o;
  if (i < total8) {
    float4 a = ((const float4*)FM)[2 * i];
    float4 b = ((const float4*)FM)[2 * i + 1];
    o[0] = (bf16)a.x; o[1] = (bf16)a.y; o[2] = (bf16)a.z; o[3] = (bf16)a.w;
    o[4] = (bf16)b.x; o[5] = (bf16)b.y; o[6] = (bf16)b.z; o[7] = (bf16)b.w;
  } else {
#pragma unroll
    for (int e = 0; e < 8; ++e) o[e] = (bf16)0.f;   // pad rows 100000..100095
  }
  ((bf16x8*)FMB)[i] = o;                   // 16B store
}

// -------------------- K3: 256^2 pipelined bf16 MFMA GEMM + top-5 ----------
__device__ __forceinline__ void gl_lds16(const bf16* g, char* l) {
  __builtin_amdgcn_global_load_lds((__attribute__((address_space(1))) void*)g,
                                   (__attribute__((address_space(3))) void*)l,
                                   16, 0, 0);
}

// stage one 128x64 half-tile (16 KB): 2 x global_load_lds(16B) per thread.
// global source is pre-swizzled (chunk j_src = j_slot ^ (row&7)); LDS dest linear.
#define STAGE_HALF(g, off, rbase, k0) do {                                     \
    gl_lds16((g) + (size_t)(rbase) * D_DIM + (k0),      lds + (off) + d0);     \
    gl_lds16((g) + (size_t)((rbase) + 64) * D_DIM + (k0), lds + (off) + d1);   \
  } while (0)

// load one A quarter (rows 2q,2q+1 x 16) into a [2][2] frag slot
#define LOAD_AFQ(dst, qi, Ab_) do {                                            \
    dst[0][0] = *(const bf16x8*)((Ab_) + (2 * (qi) + 0) * 2048 + cs0);         \
    dst[0][1] = *(const bf16x8*)((Ab_) + (2 * (qi) + 0) * 2048 + cs1);         \
    dst[1][0] = *(const bf16x8*)((Ab_) + (2 * (qi) + 1) * 2048 + cs0);         \
    dst[1][1] = *(const bf16x8*)((Ab_) + (2 * (qi) + 1) * 2048 + cs1);         \
  } while (0)

// load one B 16-col sub-block (both k-halves)
#define LOAD_BF(dst, nb, Bb_) do {                                             \
    dst[0] = *(const bf16x8*)((Bb_) + (nb) * 2048 + cs0);                      \
    dst[1] = *(const bf16x8*)((Bb_) + (nb) * 2048 + cs1);                      \
  } while (0)

// 8 MFMAs: quarter slot aq (rows r0..r0+1) x bf pair {n0,n0+1}; kk-outer order
// so the 4 first-halves are independent and the 4 second-halves are 4-back deps.
#define MMA8(aq, r0, n0) do {                                                  \
    __builtin_amdgcn_s_setprio(1);                                             \
    _Pragma("unroll") for (int kk = 0; kk < 2; ++kk)                           \
      _Pragma("unroll") for (int m = 0; m < 2; ++m)                            \
        _Pragma("unroll") for (int nb = 0; nb < 2; ++nb)                       \
          acc[(r0) + m][(n0) + nb] = MFMA16(aq[m][kk], bfr[(n0) + nb][kk],     \
                                            acc[(r0) + m][(n0) + nb]);         \
    __builtin_amdgcn_s_setprio(0);                                             \
  } while (0)

__global__ __launch_bounds__(512, 2) void k_gemm_topk(const bf16* __restrict__ X,
                                                      const bf16* __restrict__ FMB,
                                                      const int* __restrict__ IDX,
                                                      float2* __restrict__ CAND) {
  extern __shared__ char lds[];            // 128 KB: 2 buffers x (A 32K + B 32K)
  int bid = blockIdx.x;
  int xcd = bid & 7;                       // round-robin dispatch heuristic
  int jj = bid >> 3;
  int cnt = (xcd < 7) ? NT_PER_XCD : (NT_TILES - 7 * NT_PER_XCD);  // 49 / 48
  if (jj >= 4 * cnt) return;               // uniform whole-block early-out
  int nt = xcd * NT_PER_XCD + (jj >> 2);   // each XCD owns contiguous nt range
  int bt = jj & 3;                         // bt fastest: 4 siblings share B panel in L2
  size_t row0 = (size_t)bt * BM;
  size_t col0 = (size_t)nt * BN;

  int tid = threadIdx.x;
  int lane = tid & 63;
  int wv = tid >> 6;
  int wm = wv >> 2, wn = wv & 3;           // 2x4 wave grid; wave output = 128x64
  int frow = lane & 15, q = lane >> 4;
  // XOR-swizzled chunk byte offsets for ds_read_b128 (row&7 == frow&7 here)
  int cs0 = ((q ^ (frow & 7)) * 16);       // kk=0: k 0..31
  int cs1 = (((q + 4) ^ (frow & 7)) * 16); // kk=1: k 32..63

  // staging source (per-thread, l-invariant): chunk pre-swizzle
  int arow0 = tid >> 3;
  int jsrc = (tid & 7) ^ (arow0 & 7);
  const bf16* gA = X   + ((size_t)row0 + arow0) * D_DIM + jsrc * 8;
  const bf16* gB = FMB + ((size_t)col0 + arow0) * D_DIM + jsrc * 8;
  int d0 = tid * 16;                       // LDS dest byte (l=0)
  int d1 = 8192 + tid * 16;                // LDS dest byte (l=1)

  // ---- prologue: stage tile0 (loads 1-8) and tile1 (loads 9-16) ----
  STAGE_HALF(gA, 0,     0,   0);
  STAGE_HALF(gA, 16384, 128, 0);
  STAGE_HALF(gB, 32768, 0,   0);
  STAGE_HALF(gB, 49152, 128, 0);
  STAGE_HALF(gA, 65536 + 0,     0,   BKT);
  STAGE_HALF(gA, 65536 + 16384, 128, BKT);
  STAGE_HALF(gB, 65536 + 32768, 0,   BKT);
  STAGE_HALF(gB, 65536 + 49152, 128, BKT);

  f32x4 acc[8][4];
#pragma unroll
  for (int mi = 0; mi < 8; ++mi)
#pragma unroll
    for (int ni = 0; ni < 4; ++ni)
      acc[mi][ni] = (f32x4){0.f, 0.f, 0.f, 0.f};

  WAITVM(8);                               // tile0 landed; tile1 still in flight
  BARRIER();

  // fragment registers: 4 rotating A-quarter slots + full-tile B
  bf16x8 afq[4][2][2];
  bf16x8 bfr[4][2];

  // entry reads (tile 0, buf0): bf01, bf23, q0, q1
  {
    const char* Ab_ = lds + wm * 16384 + frow * 128;
    const char* Bb_ = lds + 32768 + (wn >> 1) * 16384 + (wn & 1) * 8192 + frow * 128;
    LOAD_BF(bfr[0], 0, Bb_);
    LOAD_BF(bfr[1], 1, Bb_);
    LOAD_BF(bfr[2], 2, Bb_);
    LOAD_BF(bfr[3], 3, Bb_);
    LOAD_AFQ(afq[0], 0, Ab_);
    LOAD_AFQ(afq[1], 1, Ab_);
  }

  // ---- main loop: ONE barrier per K-tile; every read group drains under MFMAs.
  // The mid-tile {lgkm0, vm0, barrier} simultaneously proves:
  //  (a) all waves' reads of buf[kt&1] drained  -> DMA(kt+2) into it is safe
  //  (b) each wave's DMA(kt+1) landed           -> buf[(kt+1)&1] readable by all
  for (int kt = 0; kt < NKT; ++kt) {
    int bo  = (kt & 1) << 16;
    int bon = ((kt + 1) & 1) << 16;
    const char* Ab  = lds + bo  + wm * 16384 + frow * 128;
    const char* Abn = lds + bon + wm * 16384 + frow * 128;
    const char* Bbn = lds + bon + 32768 + (wn >> 1) * 16384 + (wn & 1) * 8192 + frow * 128;
    bool st = (kt < NKT - 2), pf = (kt < NKT - 1);
    int k2 = (kt + 2) * BKT;

    LOAD_AFQ(afq[2], 2, Ab);          // q2(kt): drains under G0
    MMA8(afq[0], 0, 0);               // G0a: q0 · bf01
    LOAD_AFQ(afq[3], 3, Ab);          // q3(kt): drains under G0b/G1
    MMA8(afq[0], 0, 2);               // G0b: q0 · bf23
    MMA8(afq[1], 2, 0);               // G1:  q1 · bf01
    MMA8(afq[1], 2, 2);               //      q1 · bf23

    LGKM0();                          // all reads of buf[kt&1] drained (had G0-G1 cover)
    VM0();                            // DMA(kt+1) landed (one full tile of slack)
    BARRIER();

    if (st) {                         // DMA tile kt+2 into the buffer just vacated
      STAGE_HALF(gA, bo + 0,     0,   k2);
      STAGE_HALF(gA, bo + 16384, 128, k2);
      STAGE_HALF(gB, bo + 32768, 0,   k2);
      STAGE_HALF(gB, bo + 49152, 128, k2);
    }
    if (pf) LOAD_AFQ(afq[0], 0, Abn); // q0(kt+1): drains under G2/G3
    MMA8(afq[2], 4, 0);               // G2:  q2 · bf01
    MMA8(afq[2], 4, 2);               //      q2 · bf23
    if (pf) LOAD_AFQ(afq[1], 1, Abn); // q1(kt+1): drains under G3
    MMA8(afq[3], 6, 0);               // G3a: q3 · bf01
    if (pf) { LOAD_BF(bfr[0], 0, Bbn); LOAD_BF(bfr[1], 1, Bbn); }  // bf01(kt+1)
    MMA8(afq[3], 6, 2);               // G3b: q3 · bf23
    if (pf) { LOAD_BF(bfr[2], 2, Bbn); LOAD_BF(bfr[3], 3, Bbn); }  // bf23(kt+1)
  }

  // ---- epilogue 1: scores -> LDS (reuse all 128 KB as 256x256 bf16 tile) ----
  // C/D layout: frag_row=(lane>>4)*4+r, frag_col=lane&15.
  // score layout swizzled: 16B chunk index ^= (row&31) to break the 512B row stride.
  __syncthreads();
  int Rbase = wm * 128 + q * 4;
#pragma unroll
  for (int mi = 0; mi < 8; ++mi)
#pragma unroll
    for (int ni = 0; ni < 4; ++ni) {
      int Cc = wn * 64 + ni * 16 + frow;
      int chunkC = Cc >> 3;
      int e2 = (Cc & 7) * 2;
#pragma unroll
      for (int r = 0; r < 4; ++r) {
        int R = Rbase + mi * 16 + r;
        *(bf16*)(lds + R * 512 + ((chunkC ^ (R & 31)) * 16) + e2) = (bf16)acc[mi][ni][r];
      }
    }
  __syncthreads();

  // ---- epilogue 2: per-row top-5 within this 256-col tile (2 threads/row) ----
  int tr = tid >> 1, h = tid & 1;
  int grow = (int)row0 + tr;
  int self = IDX[grow];
  float tv[K_TOP]; int ti[K_TOP];
#pragma unroll
  for (int j = 0; j < K_TOP; ++j) { tv[j] = -1e30f; ti[j] = -1; }
  int swz = tr & 31;
#pragma unroll
  for (int c8 = 0; c8 < 16; ++c8) {
    int chunk = h * 16 + c8;
    bf16x8 v8 = *(const bf16x8*)(lds + tr * 512 + ((chunk ^ swz) * 16));
#pragma unroll
    for (int e = 0; e < 8; ++e) {
      int gc = (int)col0 + chunk * 8 + e;
      if (gc >= N_MEM || gc == self) continue;    // self-mask == set-to-min trick
      float v = (float)v8[e];
      if (v > tv[K_TOP - 1]) insert5(v, gc, tv, ti);
    }
  }
  // merge the two halves via lane-pair shuffle (snapshot partner first!)
  float pv[K_TOP]; int pi[K_TOP];
#pragma unroll
  for (int j = 0; j < K_TOP; ++j) {
    pv[j] = __shfl_xor(tv[j], 1, 64);
    pi[j] = __shfl_xor(ti[j], 1, 64);
  }
#pragma unroll
  for (int j = 0; j < K_TOP; ++j)
    if (pv[j] > tv[K_TOP - 1]) insert5(pv[j], pi[j], tv, ti);

  if (h == 0) {
    float2* out = CAND + ((size_t)grow * NT_TILES + nt) * K_TOP;
#pragma unroll
    for (int j = 0; j < K_TOP; ++j)
      out[j] = make_float2(tv[j], __int_as_float(ti[j]));
  }
}

// -------------------- shared epilogue: gather pred rows, mean, argmax --------------------
__device__ void gather_mean_argmax(const int* find, const float* __restrict__ P,
                                   float* __restrict__ OUT, int b, int tid) {
  float bestV = -1e30f;
  int bestC = 0;
  for (int c = tid; c < C_CLS; c += 256) {
    float s = 0.f;
    for (int j = 0; j < K_TOP; ++j) s += P[(size_t)find[j] * C_CLS + c];
    float mean = s * (1.0f / K_TOP);
    OUT[(size_t)B_ROWS + (size_t)b * C_CLS + c] = mean;
    if (mean > bestV) { bestV = mean; bestC = c; }   // strict > keeps first occurrence
  }
  __shared__ float rv[256];
  __shared__ int rc[256];
  rv[tid] = bestV; rc[tid] = bestC;
  for (int s = 128; s >= 1; s >>= 1) {
    __syncthreads();
    if (tid < s) {
      float v2 = rv[tid + s]; int c2 = rc[tid + s];
      if (v2 > rv[tid] || (v2 == rv[tid] && c2 < rc[tid])) { rv[tid] = v2; rc[tid] = c2; }
    }
  }
  __syncthreads();
  if (tid == 0) OUT[b] = (float)rc[0];   // jnp.argmax: first max index
}

// -------------------- K4: merge per-tile candidates -> global top-5 + epilogue ------
__global__ __launch_bounds__(256) void k_merge(const float2* __restrict__ CAND,
                                               const float* __restrict__ P,
                                               float* __restrict__ OUT) {
  int b = blockIdx.x;
  int tid = threadIdx.x;
  const float2* row = CAND + (size_t)b * (NT_TILES * K_TOP);

  float tv[K_TOP]; int ti[K_TOP];
  for (int j = 0; j < K_TOP; ++j) { tv[j] = -1e30f; ti[j] = -1; }
  for (int i = tid; i < NT_TILES * K_TOP; i += 256) {
    float2 e = row[i];
    float v = e.x;
    if (v > tv[K_TOP - 1]) insert5(v, __float_as_int(e.y), tv, ti);
  }

  __shared__ float sv[256 * K_TOP];
  __shared__ int si[256 * K_TOP];
  for (int j = 0; j < K_TOP; ++j) { sv[tid * K_TOP + j] = tv[j]; si[tid * K_TOP + j] = ti[j]; }
  for (int s = 128; s >= 1; s >>= 1) {
    __syncthreads();
    if (tid < s) {
      for (int j = 0; j < K_TOP; ++j) {
        float v = sv[(tid + s) * K_TOP + j];
        int n = si[(tid + s) * K_TOP + j];
        if (v > tv[K_TOP - 1]) insert5(v, n, tv, ti);
      }
      for (int j = 0; j < K_TOP; ++j) { sv[tid * K_TOP + j] = tv[j]; si[tid * K_TOP + j] = ti[j]; }
    }
  }
  __syncthreads();
  __shared__ int find[K_TOP];
  if (tid == 0)
    for (int j = 0; j < K_TOP; ++j) {
      int v = si[j];
      find[j] = (v < 0) ? 0 : (v >= N_MEM ? N_MEM - 1 : v);   // defensive clamp
    }
  __syncthreads();
  gather_mean_argmax(find, P, OUT, b, tid);
}

// -------------------- fallback (only if ws_size too small): slow but ws-free --------
__global__ __launch_bounds__(256) void k_naive(const float* __restrict__ F,
                                               const int* __restrict__ IDX,
                                               const float* __restrict__ FM,
                                               const float* __restrict__ P,
                                               float* __restrict__ OUT) {
  int b = blockIdx.x;
  int tid = threadIdx.x;
  __shared__ float wred[4];
  const float4* fr = (const float4*)(F + (size_t)b * D_DIM);
  float4 v = fr[tid];
  float s = v.x * v.x + v.y * v.y + v.z * v.z + v.w * v.w;
  for (int off = 32; off > 0; off >>= 1) s += __shfl_down(s, off, 64);
  if ((tid & 63) == 0) wred[tid >> 6] = s;
  __syncthreads();
  float inv = 1.0f / fmaxf(sqrtf(wred[0] + wred[1] + wred[2] + wred[3]), 1e-12f);
  float4 xv = make_float4(v.x * inv, v.y * inv, v.z * inv, v.w * inv);
  __syncthreads();
  int self = IDX[b];
  __shared__ float ptv[K_TOP];
  __shared__ int pti[K_TOP];
  if (tid < K_TOP) { ptv[tid] = -1e30f; pti[tid] = 0; }
  __syncthreads();
  for (int n = 0; n < N_MEM; ++n) {
    const float4* frow = (const float4*)(FM + (size_t)n * D_DIM);
    float4 fv = frow[tid];
    float p = xv.x * fv.x + xv.y * fv.y + xv.z * fv.z + xv.w * fv.w;
    for (int off = 32; off > 0; off >>= 1) p += __shfl_down(p, off, 64);
    if ((tid & 63) == 0) wred[tid >> 6] = p;
    __syncthreads();
    if (tid == 0 && n != self) {
      float tot = wred[0] + wred[1] + wred[2] + wred[3];
      if (tot > ptv[K_TOP - 1]) {
        int q = K_TOP - 1;
        while (q > 0 && tot > ptv[q - 1]) { ptv[q] = ptv[q - 1]; pti[q] = pti[q - 1]; --q; }
        ptv[q] = tot; pti[q] = n;
      }
    }
    __syncthreads();
  }
  __shared__ int find[K_TOP];
  if (tid < K_TOP) {
    int x = pti[tid];
    find[tid] = (x < 0) ? 0 : (x >= N_MEM ? N_MEM - 1 : x);
  }
  __syncthreads();
  gather_mean_argmax(find, P, OUT, b, tid);
}

// -------------------- launch --------------------
extern "C" void kernel_launch(void* const* d_in, const int* in_sizes, int n_in,
                              void* d_out, int out_size, void* d_ws, size_t ws_size,
                              hipStream_t stream) {
  const float* F  = (const float*)d_in[0];
  const int* IDX  = (const int*)d_in[1];
  const float* FM = (const float*)d_in[2];
  const float* P  = (const float*)d_in[3];
  float* OUT = (float*)d_out;

  const size_t xBytes    = (size_t)B_ROWS * D_DIM * 2;                 // 2 MB
  const size_t fmBytes   = (size_t)NPAD * D_DIM * 2;                   // ~205 MB
  const size_t candBytes = (size_t)B_ROWS * NT_TILES * K_TOP * 8;      // ~16 MB
  const size_t need = xBytes + fmBytes + candBytes;                    // ~223 MB

  if (ws_size >= need) {
    bf16* Xb     = (bf16*)d_ws;
    bf16* FMB    = (bf16*)((char*)d_ws + xBytes);
    float2* CAND = (float2*)((char*)d_ws + xBytes + fmBytes);
    // opt in to 128 KB dynamic LDS (host-side, graph-capture safe)
    (void)hipFuncSetAttribute((const void*)k_gemm_topk,
                              hipFuncAttributeMaxDynamicSharedMemorySize, 131072);
    k_normalize<<<B_ROWS, 256, 0, stream>>>(F, Xb);
    int total8 = N_MEM * D_DIM / 8;                                    // 12,800,000
    int pad8   = NPAD * D_DIM / 8;                                     // 12,812,288
    k_convert<<<(pad8 + 255) / 256, 256, 0, stream>>>(FM, FMB, total8, pad8);
    k_gemm_topk<<<GRID_GEMM, 512, 131072, stream>>>(Xb, FMB, IDX, CAND);
    k_merge<<<B_ROWS, 256, 0, stream>>>(CAND, P, OUT);
  } else {
    // diagnostic fallback: correct but slow, needs zero workspace
    k_naive<<<B_ROWS, 256, 0, stream>>>(F, IDX, FM, P, OUT);
  }
}